// Round 22
// baseline (50.411 us; speedup 1.0000x reference)
//
#include <hip/hip_runtime.h>

#define NPTS   8192
#define BATCH  32
#define CIN    64
#define COUT   64
#define RANKK  16
#define ROWS   (BATCH * CIN)   // 2048 = BATCH*COUT too
#define KB_SPLIT 16            // outer K split (Sp segments)

typedef _Float16 f16;
typedef _Float16 f16x4 __attribute__((ext_vector_type(4)));
typedef _Float16 f16x8 __attribute__((ext_vector_type(8)));
typedef float    f32x4 __attribute__((ext_vector_type(4)));

#define TWO_PI_OVER_N (6.28318530717958647692f / (float)NPTS)

__device__ __forceinline__ void gload16(const void* g, void* l) {
  __builtin_amdgcn_global_load_lds(
      (const __attribute__((address_space(1))) void*)g,
      (__attribute__((address_space(3))) void*)l, 16, 0, 0);
}

// table element (c, n):  c<64 -> cos(2*pi*c*n/N),  c>=64 -> sin(2*pi*(c-64)*n/N)
// sin(th) = cos(th - pi/2)  ->  integer phase m' = (freq*n + (c>=64)*6144) & 8191
__device__ __forceinline__ f16 trig_elem(int freq, int phase_off, int n) {
  int m = (freq * n + phase_off) & (NPTS - 1);
  return (f16)__cosf((float)m * TWO_PI_OVER_N);
}

// ---------------------------------------------------------------------------
// Kernel 1: forward "DFT" GEMM. x staged async DEPTH-3 (4 slots), T computed
// in-LDS depth-1 (2 slots). 48 KiB total -> 3 blocks/CU (unchanged vs R18),
// but 3 K-steps of x stay in flight across each barrier (counted vmcnt(2)).
//   Sp[kb][row][c] = sum_{n in K-block kb} x[row][n] * T[c][n]   (f16 partials)
// Grid = 32 row-blocks(64 rows) x 16 kb, 512 threads (8 waves).
// Same XOR-swizzle maps as R7/R15/R17/R18 (refcheck-proven).
// ---------------------------------------------------------------------------
__global__ __launch_bounds__(512) void fwd_dft(const float* __restrict__ x,
                                               f16* __restrict__ Sp) {
  __shared__ __align__(16) char xlds[4 * 8192];  // 4 x-slots (64x32 f32)
  __shared__ __align__(16) char tlds[2 * 8192];  // 2 T-slots (128x32 f16)
  const int t    = threadIdx.x;                  // 0..511
  const int w    = t >> 6;                       // 0..7
  const int lane = t & 63;
  const int rl = lane & 15, hi = lane >> 4;
  const int kb = blockIdx.x & (KB_SPLIT - 1);
  const int r0 = (blockIdx.x >> 4) * 64;       // row-block base
  const int k0 = kb * (NPTS / KB_SPLIT);       // 512-wide K range

  // x staging: one chunk per thread, pre-swizzled global source (R17 map)
  const int xr_ = t >> 3;                        // x chunk row (0..63)
  const int xo_ = ((t & 7) ^ (xr_ & 7)) << 2;    // f32 offset in 32-col step
  const float* xs0 = x + (size_t)(r0 + xr_) * NPTS + k0 + xo_;
  const int wu = w * 1024;                     // wave-uniform LDS byte base

  // T compute params: thread owns chunk t -> (trow = t>>2, cc = t&3),
  // swizzled col-group g = cc ^ (trow&3), data cols g*8..+8 (R7 map).
  const int ttrow = t >> 2, tcc = t & 3;
  const int tg   = tcc ^ (ttrow & 3);
  const int tfreq = ttrow & 63;
  const int tpo   = (ttrow < 64) ? 0 : 6144;     // cos vs sin phase offset

  auto STAGE_X = [&](int kt, int slot) {
    gload16(xs0 + kt * 32, xlds + slot * 8192 + wu);
  };
  auto STAGE_T = [&](int kt, int slot) {
    char* tb = tlds + slot * 8192;
    const int nb = k0 + kt * 32 + tg * 8;
    f16x8 v;
#pragma unroll
    for (int e = 0; e < 8; ++e) v[e] = trig_elem(tfreq, tpo, nb + e);
    *(f16x8*)(tb + t * 16) = v;
  };

  f32x4 acc[4];
#pragma unroll
  for (int i = 0; i < 4; ++i) acc[i] = (f32x4){0.f, 0.f, 0.f, 0.f};

  // swizzled read offsets (lane-constant across kt) — R17 wave split
  const int h  = w >> 1;        // row quarter (0..3)
  const int cg = w & 1;         // col half (64 cols)
  const int axr = h * 16 + rl;  // x_tile row for this lane's A fragment
  const int ad0 = (axr * 8 + ((2 * hi) ^ (axr & 7))) * 16;
  const int ad1 = (axr * 8 + ((2 * hi + 1) ^ (axr & 7))) * 16;
  int bd[4];
#pragma unroll
  for (int s = 0; s < 4; ++s) {
    int trow = cg * 64 + s * 16 + rl;
    bd[s] = (trow * 4 + (hi ^ (trow & 3))) * 16;
  }

  auto COMPUTE = [&](int kt) {
    char* xb = xlds + (kt & 3) * 8192;
    char* tb = tlds + (kt & 1) * 8192;
    f32x4 a0 = *(const f32x4*)(xb + ad0);
    f32x4 a1 = *(const f32x4*)(xb + ad1);
    f16x8 af;
#pragma unroll
    for (int j = 0; j < 4; ++j) { af[j] = (f16)a0[j]; af[4 + j] = (f16)a1[j]; }
#pragma unroll
    for (int s = 0; s < 4; ++s) {
      f16x8 bf = *(const f16x8*)(tb + bd[s]);
      acc[s] = __builtin_amdgcn_mfma_f32_16x16x32_f16(af, bf, acc[s], 0, 0, 0);
    }
  };

  // prologue: 3 x-slots in flight, T slot 0 computed
  STAGE_X(0, 0);
  STAGE_X(1, 1);
  STAGE_X(2, 2);
  STAGE_T(0, 0);
  asm volatile("s_waitcnt vmcnt(2) lgkmcnt(0)" ::: "memory");  // x0 + T0 ready
  __builtin_amdgcn_s_barrier();

  for (int kt = 0; kt < 16; ++kt) {
    if (kt + 3 < 16) STAGE_X(kt + 3, (kt + 3) & 3);  // overwrites slot read at kt-1 (post-barrier: safe)
    if (kt + 1 < 16) STAGE_T(kt + 1, (kt + 1) & 1);  // disjoint from slot read by COMPUTE(kt)
    COMPUTE(kt);
    if (kt < 15) {
      // x outstanding after issue: {kt+1..min(kt+3,15)}; need kt+1 landed
      if (kt <= 12)
        asm volatile("s_waitcnt vmcnt(2) lgkmcnt(0)" ::: "memory");
      else if (kt == 13)
        asm volatile("s_waitcnt vmcnt(1) lgkmcnt(0)" ::: "memory");
      else
        asm volatile("s_waitcnt vmcnt(0) lgkmcnt(0)" ::: "memory");
      __builtin_amdgcn_s_barrier();
    }
  }

  // epilogue: wave owns rows r0+h*16..+16, cols cg*64..+64
  f16* out = Sp + ((size_t)kb * ROWS + r0 + h * 16) * 128 + cg * 64;
#pragma unroll
  for (int s = 0; s < 4; ++s)
#pragma unroll
    for (int i = 0; i < 4; ++i)
      out[(hi * 4 + i) * 128 + s * 16 + rl] = (f16)acc[s][i];
}

// ---------------------------------------------------------------------------
// Kernel 2a: split-K partial reduction, f16 in / f32 out (R15-proven).
// ---------------------------------------------------------------------------
__global__ __launch_bounds__(256) void reduce_k(const f16* __restrict__ Sp,
                                                float* __restrict__ Sred) {
  const int idx = blockIdx.x * 256 + threadIdx.x;      // 0..65535 f16x4 idx
  const f16x4* src = (const f16x4*)Sp;
  f32x4 acc = (f32x4){0.f, 0.f, 0.f, 0.f};
#pragma unroll
  for (int s = 0; s < KB_SPLIT; ++s) {
    f16x4 v = src[(size_t)s * (ROWS * 128 / 4) + idx];
#pragma unroll
    for (int e = 0; e < 4; ++e) acc[e] += (float)v[e];
  }
  ((f32x4*)Sred)[idx] = acc;
}

// ---------------------------------------------------------------------------
// Kernel 2b: channel mix + scaling -> Qh (f16).  Grid: 32 batches x 16 o-groups.
// (R13/R15-proven structure, unchanged)
// ---------------------------------------------------------------------------
__global__ __launch_bounds__(256) void mix3(const float* __restrict__ Sred,
                                            const float* __restrict__ Ur,
                                            const float* __restrict__ Ui,
                                            const float* __restrict__ Vr,
                                            const float* __restrict__ Vi,
                                            const float* __restrict__ Sv,
                                            f16* __restrict__ Qh) {
  __shared__ float Srs[64][64], Sis[64][64];
  __shared__ float wr_s[64][4], wi_s[64][4];
  const int b  = blockIdx.x >> 4;
  const int og = blockIdx.x & 15;
  const int t  = threadIdx.x;

#pragma unroll
  for (int j = 0; j < 8; ++j) {
    int f4 = t + 256 * j;                // 0..2047 float4s
    int i = f4 >> 5, kc = (f4 & 31) * 4; // row i, col kc..kc+3
    f32x4 v = *(const f32x4*)(Sred + ((size_t)(b * 64 + i)) * 128 + kc);
    if (kc < 64) *(f32x4*)&Srs[i][kc] = v;
    else         *(f32x4*)&Sis[i][kc - 64] = v;
  }

  {
    int i = t >> 2, ol = t & 3, o = og * 4 + ol;
    float wr = 0.f, wi = 0.f;
#pragma unroll
    for (int r = 0; r < RANKK; ++r) {
      float ur = Ur[i * RANKK + r], ui = Ui[i * RANKK + r];
      float vr = Vr[r * COUT + o],  vi = Vi[r * COUT + o];
      float s = Sv[r];
      wr += s * (ur * vr - ui * vi);
      wi += s * (ur * vi + ui * vr);
    }
    wr_s[i][ol] = wr;
    wi_s[i][ol] = wi;
  }
  __syncthreads();

  const int ol = t >> 6, k = t & 63, o = og * 4 + ol;
  float qr = 0.f, qi = 0.f;
#pragma unroll 4
  for (int i = 0; i < 64; ++i) {
    float sr = Srs[i][k], si = Sis[i][k];     // stride-1 across lanes: conflict-free
    float wr = wr_s[i][ol], wi = wi_s[i][ol]; // wave-uniform broadcast
    qr += sr * wr + si * wi;
    qi += sr * wi - si * wr;
  }
  float sk = (k == 0 ? 1.0f : 2.0f) / (float)NPTS;  // c_k and both ortho 1/sqrt(N)
  f16* qrow = Qh + ((size_t)(b * 64 + o)) * 128;
  qrow[k]      = (f16)(qr * sk);
  qrow[64 + k] = (f16)(-qi * sk);
}

// ---------------------------------------------------------------------------
// Kernel 3: inverse GEMM, block-tiled, computed-in-LDS B tile (no Tt buffer).
//   y[row][n] = sum_c Qh[row][c] * table(c, n)
// (R18-proven structure, unchanged)
// ---------------------------------------------------------------------------
__global__ __launch_bounds__(256) void inv_dft(const f16* __restrict__ Qh,
                                               float* __restrict__ y) {
  __shared__ f16   Bt[64][136];    // 64 n-rows x 128 k  (+8 f16 pad)
  __shared__ float Tr[4][16][68];  // per-wave store transpose (+4 pad)
  const int t = threadIdx.x, w = t >> 6, lane = t & 63;
  const int rl = lane & 15, hi = lane >> 4;
  const int nb = blockIdx.x & 127;   // n-block (64 wide)
  const int rb = blockIdx.x >> 7;    // row-block (64 rows)
  const int n0 = nb * 64, r0 = rb * 64;

  // A fragments: rows r0 + w*16 + rl, k = 32*ksv + 8*hi (+j)
  const f16* qrow = Qh + (size_t)(r0 + w * 16 + rl) * 128 + 8 * hi;
  f16x8 af[4];
#pragma unroll
  for (int ksv = 0; ksv < 4; ++ksv) af[ksv] = *(const f16x8*)(qrow + ksv * 32);

  // compute B tile: Bt[row][c] = table(c, n0+row); chunk d = (row=d>>4, q=d&15)
#pragma unroll
  for (int j = 0; j < 4; ++j) {
    int d = j * 256 + t, row = d >> 4, q = d & 15;
    int nn = n0 + row;
    int freq0 = (q & 7) * 8;               // c&63 for e=0
    int po = (q < 8) ? 0 : 6144;           // cos rows vs sin rows
    f16x8 v;
#pragma unroll
    for (int e = 0; e < 8; ++e) v[e] = trig_elem(freq0 + e, po, nn);
    *(f16x8*)(&Bt[row][q * 8]) = v;
  }
  __syncthreads();

  f32x4 acc[4];
#pragma unroll
  for (int i = 0; i < 4; ++i) acc[i] = (f32x4){0.f, 0.f, 0.f, 0.f};

#pragma unroll
  for (int ksv = 0; ksv < 4; ++ksv)
#pragma unroll
    for (int s = 0; s < 4; ++s) {
      f16x8 bf = *(const f16x8*)(&Bt[s * 16 + rl][(ksv * 4 + hi) * 8]);
      acc[s] = __builtin_amdgcn_mfma_f32_16x16x32_f16(af[ksv], bf, acc[s], 0, 0, 0);
    }

  // epilogue: per-wave transpose in padded LDS, then coalesced float4 stores.
#pragma unroll
  for (int s = 0; s < 4; ++s)
#pragma unroll
    for (int i = 0; i < 4; ++i)
      Tr[w][hi * 4 + i][s * 16 + rl] = acc[s][i];
#pragma unroll
  for (int p = 0; p < 4; ++p) {
    int r = p * 4 + hi;
    f32x4 v = *(const f32x4*)(&Tr[w][r][rl * 4]);
    *(f32x4*)(y + (size_t)(r0 + w * 16 + r) * NPTS + n0 + rl * 4) = v;
  }
}

// ---------------------------------------------------------------------------
extern "C" void kernel_launch(void* const* d_in, const int* in_sizes, int n_in,
                              void* d_out, int out_size, void* d_ws, size_t ws_size,
                              hipStream_t stream) {
  const float* x  = (const float*)d_in[0];
  const float* Ur = (const float*)d_in[1];
  const float* Ui = (const float*)d_in[2];
  const float* Vr = (const float*)d_in[3];
  const float* Vi = (const float*)d_in[4];
  const float* Sv = (const float*)d_in[5];
  float* y = (float*)d_out;
  char* ws = (char*)d_ws;

  // workspace layout (9.5 MiB total):
  f16*   Sp   = (f16*)ws;                              // KB_SPLIT * 512 KiB = 8 MiB
  char*  p    = ws + (size_t)KB_SPLIT * ROWS * 128 * 2;
  float* Sred = (float*)p;                             // 1 MiB
  f16*   Qh   = (f16*)(p + (size_t)ROWS * 128 * 4);    // 512 KiB

  fwd_dft<<<(ROWS / 64) * KB_SPLIT, 512, 0, stream>>>(x, Sp);
  reduce_k<<<ROWS * 128 / 4 / 256, 256, 0, stream>>>(Sp, Sred);
  mix3<<<BATCH * 16, 256, 0, stream>>>(Sred, Ur, Ui, Vr, Vi, Sv, Qh);
  inv_dft<<<(ROWS / 64) * (NPTS / 64), 256, 0, stream>>>(Qh, y);
}